// Round 4
// baseline (1081.631 us; speedup 1.0000x reference)
//
#include <hip/hip_runtime.h>
#include <hip/hip_bf16.h>

// ---------------------------------------------------------------------------
// GNN regression: per timestep t: 3x GCNConv(relu) then edge-MLP head.
//   edge head: relu(concat(x[s],x[d],ea)@We + be) . Wg
//            = relu(u[s] + v[d] + ea@We_ea + be) . Wg   with u=x@We[:128], v=x@We[128:256]
//   GCN agg:   CSR-by-dst gather; matmul epilogue pre-scales rows by dinv;
//              gather fuses self-loop+bias+relu.
// NOTE: reference rebinds W1=W2 after t=0 (`W1 = W2; W1 = W1`).
// R2: edge_mlp LDS-staged + unrolled (375->124us).
// R3: matmul rewritten: 64x128 block, 8x4 acc/thread, BK=32, xs transposed so
//     per-k LDS = 3x ds_read_b128 (36cyc) vs 32 FMA (64cyc) -> FMA-bound.
//     Old 32-row tile was LDS-issue-bound (~45us); predict ~18-22us.
//     edge_mlp: unroll deepened to 8 edges/group-iter (16 gathers in flight).
// ---------------------------------------------------------------------------

#define BM 64
#define BK 32

__global__ __launch_bounds__(256) void matmul128(
    const float* __restrict__ X, const float* __restrict__ W,
    float* __restrict__ out, const float* __restrict__ scale,
    int n_rows, int out_stride, int out_off)
{
    __shared__ float xs[BK][BM + 4];    // [k][row], +4 keeps 16B align, no conflicts
    __shared__ float ws[BK][128 + 4];
    const int tid = threadIdx.x;
    const int r0  = blockIdx.x * BM;
    const int tr  = tid >> 5;   // 0..7  -> rows tr*8..tr*8+7
    const int tc  = tid & 31;   // cols tc*4..tc*4+3

    float acc[8][4] = {};

    for (int k0 = 0; k0 < 128; k0 += BK) {
        // stage X tile (64 rows x 32 k), transposed into xs[k][row]
        {
            int r  = tid & 63;
            int f0 = tid >> 6;            // 0..3
            int gr = r0 + r;
            #pragma unroll
            for (int it = 0; it < 2; ++it) {
                int f4 = f0 + it * 4;     // 0..7 -> k-offset f4*4
                float4 xv = make_float4(0.f, 0.f, 0.f, 0.f);
                if (gr < n_rows)
                    xv = *(const float4*)(X + (size_t)gr * 128 + k0 + f4 * 4);
                xs[f4 * 4 + 0][r] = xv.x; xs[f4 * 4 + 1][r] = xv.y;
                xs[f4 * 4 + 2][r] = xv.z; xs[f4 * 4 + 3][r] = xv.w;
            }
        }
        // stage W tile (32 k x 128 cols)
        {
            int c4 = (tid & 31) * 4;
            int kb = tid >> 5;            // 0..7
            #pragma unroll
            for (int it = 0; it < 4; ++it) {
                int k = kb + it * 8;      // 0..31
                *(float4*)(&ws[k][c4]) =
                    *(const float4*)(W + (size_t)(k0 + k) * 128 + c4);
            }
        }
        __syncthreads();
        #pragma unroll
        for (int k = 0; k < BK; ++k) {
            float4 xv0 = *(const float4*)(&xs[k][tr * 8]);
            float4 xv1 = *(const float4*)(&xs[k][tr * 8 + 4]);
            float4 wv  = *(const float4*)(&ws[k][tc * 4]);
            float xr[8] = {xv0.x, xv0.y, xv0.z, xv0.w, xv1.x, xv1.y, xv1.z, xv1.w};
            #pragma unroll
            for (int i = 0; i < 8; ++i) {
                acc[i][0] = fmaf(xr[i], wv.x, acc[i][0]);
                acc[i][1] = fmaf(xr[i], wv.y, acc[i][1]);
                acc[i][2] = fmaf(xr[i], wv.z, acc[i][2]);
                acc[i][3] = fmaf(xr[i], wv.w, acc[i][3]);
            }
        }
        __syncthreads();
    }

    #pragma unroll
    for (int i = 0; i < 8; ++i) {
        int gr = r0 + tr * 8 + i;
        if (gr >= n_rows) continue;
        float s = scale ? scale[gr] : 1.0f;
        float4 o = make_float4(acc[i][0] * s, acc[i][1] * s,
                               acc[i][2] * s, acc[i][3] * s);
        *(float4*)(out + (size_t)gr * out_stride + out_off + tc * 4) = o;
    }
}

// x_new[n] = relu( dinv[n] * (hs[n] + sum_{e in in(n)} hs[src_e]) + b )
__global__ __launch_bounds__(256) void gcn_gather(
    const float* __restrict__ hs, const int* __restrict__ csr_src,
    const int* __restrict__ offs, const int* __restrict__ counts,
    const float* __restrict__ dinv, const float* __restrict__ bias,
    float* __restrict__ xout, int n)
{
    int node = blockIdx.x * 8 + (threadIdx.x >> 5);
    if (node >= n) return;
    int lane = threadIdx.x & 31;
    int c = lane * 4;
    int off = offs[node];
    int cnt = counts[node];

    float4 a = *(const float4*)(hs + (size_t)node * 128 + c);  // self term
    int j = 0;
    for (; j + 4 <= cnt; j += 4) {
        int s0 = csr_src[off + j + 0];
        int s1 = csr_src[off + j + 1];
        int s2 = csr_src[off + j + 2];
        int s3 = csr_src[off + j + 3];
        float4 h0 = *(const float4*)(hs + (size_t)s0 * 128 + c);
        float4 h1 = *(const float4*)(hs + (size_t)s1 * 128 + c);
        float4 h2 = *(const float4*)(hs + (size_t)s2 * 128 + c);
        float4 h3 = *(const float4*)(hs + (size_t)s3 * 128 + c);
        a.x += h0.x + h1.x + h2.x + h3.x;
        a.y += h0.y + h1.y + h2.y + h3.y;
        a.z += h0.z + h1.z + h2.z + h3.z;
        a.w += h0.w + h1.w + h2.w + h3.w;
    }
    for (; j < cnt; ++j) {
        int s = csr_src[off + j];
        float4 hv = *(const float4*)(hs + (size_t)s * 128 + c);
        a.x += hv.x; a.y += hv.y; a.z += hv.z; a.w += hv.w;
    }
    float dn = dinv[node];
    float4 bb = *(const float4*)(bias + c);
    float4 o;
    o.x = fmaxf(fmaf(a.x, dn, bb.x), 0.f);
    o.y = fmaxf(fmaf(a.y, dn, bb.y), 0.f);
    o.z = fmaxf(fmaf(a.z, dn, bb.z), 0.f);
    o.w = fmaxf(fmaf(a.w, dn, bb.w), 0.f);
    *(float4*)(xout + (size_t)node * 128 + c) = o;
}

// acc += sum_e relu(u[src_e] + v[dst_e] + ea_e@We_ea + be) . Wg
#define EM_CHUNK 256
__global__ __launch_bounds__(256) void edge_mlp(
    const float* __restrict__ uv, const int* __restrict__ src,
    const int* __restrict__ dst, const float* __restrict__ ea,
    const float* __restrict__ We_e, const float* __restrict__ be,
    const float* __restrict__ Wg, float* __restrict__ acc, int E)
{
    const int tid = threadIdx.x;
    const int c   = tid & 127;   // channel
    const int g   = tid >> 7;    // group 0/1

    __shared__ float eas[EM_CHUNK * 7];
    __shared__ int   ss[EM_CHUNK];
    __shared__ int   ds[EM_CHUNK];
    __shared__ float red[256];

    float w0 = We_e[0 * 128 + c], w1 = We_e[1 * 128 + c],
          w2 = We_e[2 * 128 + c], w3 = We_e[3 * 128 + c],
          w4 = We_e[4 * 128 + c], w5 = We_e[5 * 128 + c],
          w6 = We_e[6 * 128 + c];
    const float bec = be[c], wgc = Wg[c];

    float partial = 0.f;
    for (int base = blockIdx.x * EM_CHUNK; base < E; base += gridDim.x * EM_CHUNK) {
        const int nch = min(EM_CHUNK, E - base);
        for (int i = tid; i < nch * 7; i += 256)
            eas[i] = ea[(size_t)base * 7 + i];
        for (int i = tid; i < nch; i += 256) {
            ss[i] = src[base + i];
            ds[i] = dst[base + i];
        }
        __syncthreads();

        auto edge_val = [&](int j) -> float {
            float uvs = uv[(size_t)ss[j] * 256 + c];
            float uvd = uv[(size_t)ds[j] * 256 + 128 + c];
            const float* eav = &eas[j * 7];
            float val = uvs + uvd + bec;
            val = fmaf(eav[0], w0, val); val = fmaf(eav[1], w1, val);
            val = fmaf(eav[2], w2, val); val = fmaf(eav[3], w3, val);
            val = fmaf(eav[4], w4, val); val = fmaf(eav[5], w5, val);
            val = fmaf(eav[6], w6, val);
            return fmaxf(val, 0.f);
        };

        int j = g;
        #pragma unroll 2
        for (; j + 16 <= nch; j += 16) {  // 8 edges/group/iter -> 16 gathers in flight
            partial += edge_val(j)      + edge_val(j + 2)  + edge_val(j + 4)  + edge_val(j + 6)
                     + edge_val(j + 8)  + edge_val(j + 10) + edge_val(j + 12) + edge_val(j + 14);
        }
        for (; j < nch; j += 2)
            partial += edge_val(j);
        __syncthreads();
    }

    partial *= wgc;
    red[tid] = partial;
    __syncthreads();
    for (int s = 128; s > 0; s >>= 1) {
        if (tid < s) red[tid] += red[tid + s];
        __syncthreads();
    }
    if (tid == 0) atomicAdd(acc, red[0]);
}

// ---------------- CSR build ----------------
__global__ void count_edges(const int* __restrict__ dst, int* __restrict__ counts, int E)
{
    int e = blockIdx.x * 256 + threadIdx.x;
    if (e < E) atomicAdd(&counts[dst[e]], 1);
}

__global__ void compute_dinv(const int* __restrict__ counts, float* __restrict__ dinv, int n)
{
    int i = blockIdx.x * 256 + threadIdx.x;
    if (i < n) dinv[i] = rsqrtf((float)counts[i] + 1.0f);
}

__global__ void scan1(const int* __restrict__ counts, int* __restrict__ scanned,
                      int* __restrict__ btot, int n)
{
    __shared__ int sh[256];
    int i = blockIdx.x * 256 + threadIdx.x;
    int v = (i < n) ? counts[i] : 0;
    sh[threadIdx.x] = v;
    __syncthreads();
    for (int off = 1; off < 256; off <<= 1) {
        int t = (threadIdx.x >= off) ? sh[threadIdx.x - off] : 0;
        __syncthreads();
        sh[threadIdx.x] += t;
        __syncthreads();
    }
    if (i < n) scanned[i] = sh[threadIdx.x] - v;  // exclusive
    if (threadIdx.x == 255) btot[blockIdx.x] = sh[255];
}

__global__ void scan2(int* __restrict__ btot, int nb)
{
    __shared__ int sh[256];
    int v = (threadIdx.x < nb) ? btot[threadIdx.x] : 0;
    sh[threadIdx.x] = v;
    __syncthreads();
    for (int off = 1; off < 256; off <<= 1) {
        int t = (threadIdx.x >= off) ? sh[threadIdx.x - off] : 0;
        __syncthreads();
        sh[threadIdx.x] += t;
        __syncthreads();
    }
    if (threadIdx.x < nb) btot[threadIdx.x] = sh[threadIdx.x] - v;  // exclusive
}

__global__ void scan3(const int* __restrict__ scanned, const int* __restrict__ btot,
                      int* __restrict__ offs, int* __restrict__ cursor, int n)
{
    int i = blockIdx.x * 256 + threadIdx.x;
    if (i < n) {
        int o = scanned[i] + btot[blockIdx.x];
        offs[i] = o;
        cursor[i] = o;
    }
}

__global__ void fill_csr(const int* __restrict__ src, const int* __restrict__ dst,
                         int* __restrict__ cursor, int* __restrict__ csr_src, int E)
{
    int e = blockIdx.x * 256 + threadIdx.x;
    if (e < E) {
        int slot = atomicAdd(&cursor[dst[e]], 1);
        csr_src[slot] = src[e];
    }
}

__global__ void write_out(const float* __restrict__ acc, const float* __restrict__ bg,
                          float* __restrict__ out, float invE, int T)
{
    int t = threadIdx.x;
    if (t < T) out[t] = acc[t] * invE + bg[0];
}

// ---------------------------------------------------------------------------

extern "C" void kernel_launch(void* const* d_in, const int* in_sizes, int n_in,
                              void* d_out, int out_size, void* d_ws, size_t ws_size,
                              hipStream_t stream)
{
    const float* x   = (const float*)d_in[0];
    const int*  eidx = (const int*)d_in[1];
    const float* ea  = (const float*)d_in[2];
    const float* W1  = (const float*)d_in[3];
    const float* b1  = (const float*)d_in[4];
    const float* W2  = (const float*)d_in[5];
    const float* b2  = (const float*)d_in[6];
    const float* W3  = (const float*)d_in[7];
    const float* b3  = (const float*)d_in[8];
    const float* We  = (const float*)d_in[9];
    const float* be  = (const float*)d_in[10];
    const float* Wg  = (const float*)d_in[11];
    const float* bg  = (const float*)d_in[12];

    const int N = in_sizes[0] / 128;
    const int E = in_sizes[1] / 2;
    const int T = in_sizes[2] / (E * 7);
    const int* src = eidx;
    const int* dst = eidx + E;

    char* wsp = (char*)d_ws;
    auto alloc = [&](size_t bytes) -> char* {
        char* p = wsp;
        wsp += (bytes + 255) / 256 * 256;
        return p;
    };
    int*   counts  = (int*)alloc((size_t)N * 4);
    int*   offs    = (int*)alloc((size_t)N * 4);
    int*   cursor  = (int*)alloc((size_t)N * 4);
    int*   scanned = (int*)alloc((size_t)N * 4);
    int*   btot    = (int*)alloc(1024);
    int*   csr_src = (int*)alloc((size_t)E * 4);
    float* dinv    = (float*)alloc((size_t)N * 4);
    float* acc     = (float*)alloc(256);
    float* A       = (float*)alloc((size_t)N * 128 * 4);  // evolving x
    float* B       = (float*)alloc((size_t)N * 256 * 4);  // hs / uv

    hipMemsetAsync(counts, 0, (size_t)N * 4, stream);
    hipMemsetAsync(acc, 0, (size_t)T * 4, stream);

    count_edges<<<(E + 255) / 256, 256, 0, stream>>>(dst, counts, E);
    compute_dinv<<<(N + 255) / 256, 256, 0, stream>>>(counts, dinv, N);
    const int nb = (N + 255) / 256;
    scan1<<<nb, 256, 0, stream>>>(counts, scanned, btot, N);
    scan2<<<1, 256, 0, stream>>>(btot, nb);
    scan3<<<nb, 256, 0, stream>>>(scanned, btot, offs, cursor, N);
    fill_csr<<<(E + 255) / 256, 256, 0, stream>>>(src, dst, cursor, csr_src, E);

    const int mmb = (N + BM - 1) / BM;
    const int ngb = (N + 7) / 8;
    const int emb = (E + EM_CHUNK - 1) / EM_CHUNK;

    for (int t = 0; t < T; ++t) {
        const float* xin = (t == 0) ? x : A;
        const float* Wc1 = (t == 0) ? W1 : W2;  // reference rebinds W1=W2 after t=0
        matmul128<<<mmb, 256, 0, stream>>>(xin, Wc1, B, dinv, N, 128, 0);
        gcn_gather<<<ngb, 256, 0, stream>>>(B, csr_src, offs, counts, dinv, b1, A, N);
        matmul128<<<mmb, 256, 0, stream>>>(A, W2, B, dinv, N, 128, 0);
        gcn_gather<<<ngb, 256, 0, stream>>>(B, csr_src, offs, counts, dinv, b2, A, N);
        matmul128<<<mmb, 256, 0, stream>>>(A, W3, B, dinv, N, 128, 0);
        gcn_gather<<<ngb, 256, 0, stream>>>(B, csr_src, offs, counts, dinv, b3, A, N);
        matmul128<<<mmb, 256, 0, stream>>>(A, We, B, nullptr, N, 256, 0);
        matmul128<<<mmb, 256, 0, stream>>>(A, We + 128 * 128, B, nullptr, N, 256, 128);
        edge_mlp<<<emb, 256, 0, stream>>>(B, src, dst, ea + (size_t)t * E * 7,
                                          We + 256 * 128, be, Wg, acc + t, E);
    }
    write_out<<<1, 64, 0, stream>>>(acc, bg, (float*)d_out, 1.0f / (float)E, T);
}

// Round 5
// 841.574 us; speedup vs baseline: 1.2852x; 1.2852x over previous
//
#include <hip/hip_runtime.h>
#include <hip/hip_bf16.h>

// ---------------------------------------------------------------------------
// GNN regression: per timestep t: 3x GCNConv(relu) then edge-MLP head.
//   edge head: relu(concat(x[s],x[d],ea)@We + be) . Wg
//            = relu(u[s] + v[d] + ea@We_ea + be) . Wg   with u=x@We[:128], v=x@We[128:256]
//   GCN agg:   CSR-by-dst gather; matmul epilogue pre-scales rows by dinv;
//              gather fuses self-loop+bias+relu.
// NOTE: reference rebinds W1=W2 after t=0 (`W1 = W2; W1 = W1`).
// R2: edge_mlp LDS-staged + unrolled (375->124us).
// R3: matmul 64x128 reg-blocked; NEUTRAL -> matmuls were never the bottleneck;
//     remaining time is gcn_gather x6 (same random-row pattern as edge_mlp).
// R4: bf16 storage for gathered tables (hs, uv): matmul writes bf16 RNE,
//     gather/edge_mlp read bf16 + fp32 accumulate. Halves random-gather bytes
//     everywhere. Output error est ~1e-5 vs 1.1e-3 threshold (mean over 800k
//     edges averages node-correlated quantization noise).
// ---------------------------------------------------------------------------

#define BM 64
#define BK 32

__device__ __forceinline__ unsigned short f2bf(float f) {
    union { float f; unsigned int u; } v; v.f = f;
    unsigned int r = v.u + 0x7fffu + ((v.u >> 16) & 1u);  // RNE
    return (unsigned short)(r >> 16);
}
__device__ __forceinline__ float bf2f(unsigned short h) {
    union { unsigned int u; float f; } v; v.u = ((unsigned int)h) << 16;
    return v.f;
}

// out[r][c] = sum_k X[r][k]*W[k][c], optional row scale, bf16 output.
__global__ __launch_bounds__(256) void matmul128(
    const float* __restrict__ X, const float* __restrict__ W,
    unsigned short* __restrict__ out, const float* __restrict__ scale,
    int n_rows, int out_stride, int out_off)
{
    __shared__ float xs[BK][BM + 4];
    __shared__ float ws[BK][128 + 4];
    const int tid = threadIdx.x;
    const int r0  = blockIdx.x * BM;
    const int tr  = tid >> 5;   // 0..7  -> rows tr*8..tr*8+7
    const int tc  = tid & 31;   // cols tc*4..tc*4+3

    float acc[8][4] = {};

    for (int k0 = 0; k0 < 128; k0 += BK) {
        {
            int r  = tid & 63;
            int f0 = tid >> 6;            // 0..3
            int gr = r0 + r;
            #pragma unroll
            for (int it = 0; it < 2; ++it) {
                int f4 = f0 + it * 4;     // 0..7 -> k-offset f4*4
                float4 xv = make_float4(0.f, 0.f, 0.f, 0.f);
                if (gr < n_rows)
                    xv = *(const float4*)(X + (size_t)gr * 128 + k0 + f4 * 4);
                xs[f4 * 4 + 0][r] = xv.x; xs[f4 * 4 + 1][r] = xv.y;
                xs[f4 * 4 + 2][r] = xv.z; xs[f4 * 4 + 3][r] = xv.w;
            }
        }
        {
            int c4 = (tid & 31) * 4;
            int kb = tid >> 5;            // 0..7
            #pragma unroll
            for (int it = 0; it < 4; ++it) {
                int k = kb + it * 8;      // 0..31
                *(float4*)(&ws[k][c4]) =
                    *(const float4*)(W + (size_t)(k0 + k) * 128 + c4);
            }
        }
        __syncthreads();
        #pragma unroll
        for (int k = 0; k < BK; ++k) {
            float4 xv0 = *(const float4*)(&xs[k][tr * 8]);
            float4 xv1 = *(const float4*)(&xs[k][tr * 8 + 4]);
            float4 wv  = *(const float4*)(&ws[k][tc * 4]);
            float xr[8] = {xv0.x, xv0.y, xv0.z, xv0.w, xv1.x, xv1.y, xv1.z, xv1.w};
            #pragma unroll
            for (int i = 0; i < 8; ++i) {
                acc[i][0] = fmaf(xr[i], wv.x, acc[i][0]);
                acc[i][1] = fmaf(xr[i], wv.y, acc[i][1]);
                acc[i][2] = fmaf(xr[i], wv.z, acc[i][2]);
                acc[i][3] = fmaf(xr[i], wv.w, acc[i][3]);
            }
        }
        __syncthreads();
    }

    #pragma unroll
    for (int i = 0; i < 8; ++i) {
        int gr = r0 + tr * 8 + i;
        if (gr >= n_rows) continue;
        float s = scale ? scale[gr] : 1.0f;
        ushort4 o;
        o.x = f2bf(acc[i][0] * s); o.y = f2bf(acc[i][1] * s);
        o.z = f2bf(acc[i][2] * s); o.w = f2bf(acc[i][3] * s);
        *(ushort4*)(out + (size_t)gr * out_stride + out_off + tc * 4) = o;
    }
}

// x_new[n] = relu( dinv[n] * (hs[n] + sum_{e in in(n)} hs[src_e]) + b )
// hs is bf16 (pre-scaled by dinv[row] in matmul); accumulate fp32.
__global__ __launch_bounds__(256) void gcn_gather(
    const unsigned short* __restrict__ hs, const int* __restrict__ csr_src,
    const int* __restrict__ offs, const int* __restrict__ counts,
    const float* __restrict__ dinv, const float* __restrict__ bias,
    float* __restrict__ xout, int n)
{
    int node = blockIdx.x * 8 + (threadIdx.x >> 5);
    if (node >= n) return;
    int lane = threadIdx.x & 31;
    int c = lane * 4;
    int off = offs[node];
    int cnt = counts[node];

    ushort4 sv = *(const ushort4*)(hs + (size_t)node * 128 + c);  // self term
    float ax = bf2f(sv.x), ay = bf2f(sv.y), az = bf2f(sv.z), aw = bf2f(sv.w);
    int j = 0;
    for (; j + 4 <= cnt; j += 4) {
        int s0 = csr_src[off + j + 0];
        int s1 = csr_src[off + j + 1];
        int s2 = csr_src[off + j + 2];
        int s3 = csr_src[off + j + 3];
        ushort4 h0 = *(const ushort4*)(hs + (size_t)s0 * 128 + c);
        ushort4 h1 = *(const ushort4*)(hs + (size_t)s1 * 128 + c);
        ushort4 h2 = *(const ushort4*)(hs + (size_t)s2 * 128 + c);
        ushort4 h3 = *(const ushort4*)(hs + (size_t)s3 * 128 + c);
        ax += bf2f(h0.x) + bf2f(h1.x) + bf2f(h2.x) + bf2f(h3.x);
        ay += bf2f(h0.y) + bf2f(h1.y) + bf2f(h2.y) + bf2f(h3.y);
        az += bf2f(h0.z) + bf2f(h1.z) + bf2f(h2.z) + bf2f(h3.z);
        aw += bf2f(h0.w) + bf2f(h1.w) + bf2f(h2.w) + bf2f(h3.w);
    }
    for (; j < cnt; ++j) {
        int s = csr_src[off + j];
        ushort4 hv = *(const ushort4*)(hs + (size_t)s * 128 + c);
        ax += bf2f(hv.x); ay += bf2f(hv.y); az += bf2f(hv.z); aw += bf2f(hv.w);
    }
    float dn = dinv[node];
    float4 bb = *(const float4*)(bias + c);
    float4 o;
    o.x = fmaxf(fmaf(ax, dn, bb.x), 0.f);
    o.y = fmaxf(fmaf(ay, dn, bb.y), 0.f);
    o.z = fmaxf(fmaf(az, dn, bb.z), 0.f);
    o.w = fmaxf(fmaf(aw, dn, bb.w), 0.f);
    *(float4*)(xout + (size_t)node * 128 + c) = o;
}

// acc += sum_e relu(u[src_e] + v[dst_e] + ea_e@We_ea + be) . Wg   (uv bf16)
#define EM_CHUNK 256
__global__ __launch_bounds__(256) void edge_mlp(
    const unsigned short* __restrict__ uv, const int* __restrict__ src,
    const int* __restrict__ dst, const float* __restrict__ ea,
    const float* __restrict__ We_e, const float* __restrict__ be,
    const float* __restrict__ Wg, float* __restrict__ acc, int E)
{
    const int tid = threadIdx.x;
    const int c   = tid & 127;   // channel
    const int g   = tid >> 7;    // group 0/1

    __shared__ float eas[EM_CHUNK * 7];
    __shared__ int   ss[EM_CHUNK];
    __shared__ int   ds[EM_CHUNK];
    __shared__ float red[256];

    float w0 = We_e[0 * 128 + c], w1 = We_e[1 * 128 + c],
          w2 = We_e[2 * 128 + c], w3 = We_e[3 * 128 + c],
          w4 = We_e[4 * 128 + c], w5 = We_e[5 * 128 + c],
          w6 = We_e[6 * 128 + c];
    const float bec = be[c], wgc = Wg[c];

    float partial = 0.f;
    for (int base = blockIdx.x * EM_CHUNK; base < E; base += gridDim.x * EM_CHUNK) {
        const int nch = min(EM_CHUNK, E - base);
        for (int i = tid; i < nch * 7; i += 256)
            eas[i] = ea[(size_t)base * 7 + i];
        for (int i = tid; i < nch; i += 256) {
            ss[i] = src[base + i];
            ds[i] = dst[base + i];
        }
        __syncthreads();

        auto edge_val = [&](int j) -> float {
            float uvs = bf2f(uv[(size_t)ss[j] * 256 + c]);
            float uvd = bf2f(uv[(size_t)ds[j] * 256 + 128 + c]);
            const float* eav = &eas[j * 7];
            float val = uvs + uvd + bec;
            val = fmaf(eav[0], w0, val); val = fmaf(eav[1], w1, val);
            val = fmaf(eav[2], w2, val); val = fmaf(eav[3], w3, val);
            val = fmaf(eav[4], w4, val); val = fmaf(eav[5], w5, val);
            val = fmaf(eav[6], w6, val);
            return fmaxf(val, 0.f);
        };

        int j = g;
        #pragma unroll 2
        for (; j + 16 <= nch; j += 16) {
            partial += edge_val(j)      + edge_val(j + 2)  + edge_val(j + 4)  + edge_val(j + 6)
                     + edge_val(j + 8)  + edge_val(j + 10) + edge_val(j + 12) + edge_val(j + 14);
        }
        for (; j < nch; j += 2)
            partial += edge_val(j);
        __syncthreads();
    }

    partial *= wgc;
    red[tid] = partial;
    __syncthreads();
    for (int s = 128; s > 0; s >>= 1) {
        if (tid < s) red[tid] += red[tid + s];
        __syncthreads();
    }
    if (tid == 0) atomicAdd(acc, red[0]);
}

// ---------------- CSR build ----------------
__global__ void count_edges(const int* __restrict__ dst, int* __restrict__ counts, int E)
{
    int e = blockIdx.x * 256 + threadIdx.x;
    if (e < E) atomicAdd(&counts[dst[e]], 1);
}

__global__ void compute_dinv(const int* __restrict__ counts, float* __restrict__ dinv, int n)
{
    int i = blockIdx.x * 256 + threadIdx.x;
    if (i < n) dinv[i] = rsqrtf((float)counts[i] + 1.0f);
}

__global__ void scan1(const int* __restrict__ counts, int* __restrict__ scanned,
                      int* __restrict__ btot, int n)
{
    __shared__ int sh[256];
    int i = blockIdx.x * 256 + threadIdx.x;
    int v = (i < n) ? counts[i] : 0;
    sh[threadIdx.x] = v;
    __syncthreads();
    for (int off = 1; off < 256; off <<= 1) {
        int t = (threadIdx.x >= off) ? sh[threadIdx.x - off] : 0;
        __syncthreads();
        sh[threadIdx.x] += t;
        __syncthreads();
    }
    if (i < n) scanned[i] = sh[threadIdx.x] - v;  // exclusive
    if (threadIdx.x == 255) btot[blockIdx.x] = sh[255];
}

__global__ void scan2(int* __restrict__ btot, int nb)
{
    __shared__ int sh[256];
    int v = (threadIdx.x < nb) ? btot[threadIdx.x] : 0;
    sh[threadIdx.x] = v;
    __syncthreads();
    for (int off = 1; off < 256; off <<= 1) {
        int t = (threadIdx.x >= off) ? sh[threadIdx.x - off] : 0;
        __syncthreads();
        sh[threadIdx.x] += t;
        __syncthreads();
    }
    if (threadIdx.x < nb) btot[threadIdx.x] = sh[threadIdx.x] - v;  // exclusive
}

__global__ void scan3(const int* __restrict__ scanned, const int* __restrict__ btot,
                      int* __restrict__ offs, int* __restrict__ cursor, int n)
{
    int i = blockIdx.x * 256 + threadIdx.x;
    if (i < n) {
        int o = scanned[i] + btot[blockIdx.x];
        offs[i] = o;
        cursor[i] = o;
    }
}

__global__ void fill_csr(const int* __restrict__ src, const int* __restrict__ dst,
                         int* __restrict__ cursor, int* __restrict__ csr_src, int E)
{
    int e = blockIdx.x * 256 + threadIdx.x;
    if (e < E) {
        int slot = atomicAdd(&cursor[dst[e]], 1);
        csr_src[slot] = src[e];
    }
}

__global__ void write_out(const float* __restrict__ acc, const float* __restrict__ bg,
                          float* __restrict__ out, float invE, int T)
{
    int t = threadIdx.x;
    if (t < T) out[t] = acc[t] * invE + bg[0];
}

// ---------------------------------------------------------------------------

extern "C" void kernel_launch(void* const* d_in, const int* in_sizes, int n_in,
                              void* d_out, int out_size, void* d_ws, size_t ws_size,
                              hipStream_t stream)
{
    const float* x   = (const float*)d_in[0];
    const int*  eidx = (const int*)d_in[1];
    const float* ea  = (const float*)d_in[2];
    const float* W1  = (const float*)d_in[3];
    const float* b1  = (const float*)d_in[4];
    const float* W2  = (const float*)d_in[5];
    const float* b2  = (const float*)d_in[6];
    const float* W3  = (const float*)d_in[7];
    const float* b3  = (const float*)d_in[8];
    const float* We  = (const float*)d_in[9];
    const float* be  = (const float*)d_in[10];
    const float* Wg  = (const float*)d_in[11];
    const float* bg  = (const float*)d_in[12];

    const int N = in_sizes[0] / 128;
    const int E = in_sizes[1] / 2;
    const int T = in_sizes[2] / (E * 7);
    const int* src = eidx;
    const int* dst = eidx + E;

    char* wsp = (char*)d_ws;
    auto alloc = [&](size_t bytes) -> char* {
        char* p = wsp;
        wsp += (bytes + 255) / 256 * 256;
        return p;
    };
    int*   counts  = (int*)alloc((size_t)N * 4);
    int*   offs    = (int*)alloc((size_t)N * 4);
    int*   cursor  = (int*)alloc((size_t)N * 4);
    int*   scanned = (int*)alloc((size_t)N * 4);
    int*   btot    = (int*)alloc(1024);
    int*   csr_src = (int*)alloc((size_t)E * 4);
    float* dinv    = (float*)alloc((size_t)N * 4);
    float* acc     = (float*)alloc(256);
    float* A       = (float*)alloc((size_t)N * 128 * 4);          // evolving x (fp32)
    unsigned short* B = (unsigned short*)alloc((size_t)N * 256 * 2);  // hs/uv (bf16)

    hipMemsetAsync(counts, 0, (size_t)N * 4, stream);
    hipMemsetAsync(acc, 0, (size_t)T * 4, stream);

    count_edges<<<(E + 255) / 256, 256, 0, stream>>>(dst, counts, E);
    compute_dinv<<<(N + 255) / 256, 256, 0, stream>>>(counts, dinv, N);
    const int nb = (N + 255) / 256;
    scan1<<<nb, 256, 0, stream>>>(counts, scanned, btot, N);
    scan2<<<1, 256, 0, stream>>>(btot, nb);
    scan3<<<nb, 256, 0, stream>>>(scanned, btot, offs, cursor, N);
    fill_csr<<<(E + 255) / 256, 256, 0, stream>>>(src, dst, cursor, csr_src, E);

    const int mmb = (N + BM - 1) / BM;
    const int ngb = (N + 7) / 8;
    const int emb = (E + EM_CHUNK - 1) / EM_CHUNK;

    for (int t = 0; t < T; ++t) {
        const float* xin = (t == 0) ? x : A;
        const float* Wc1 = (t == 0) ? W1 : W2;  // reference rebinds W1=W2 after t=0
        matmul128<<<mmb, 256, 0, stream>>>(xin, Wc1, B, dinv, N, 128, 0);
        gcn_gather<<<ngb, 256, 0, stream>>>(B, csr_src, offs, counts, dinv, b1, A, N);
        matmul128<<<mmb, 256, 0, stream>>>(A, W2, B, dinv, N, 128, 0);
        gcn_gather<<<ngb, 256, 0, stream>>>(B, csr_src, offs, counts, dinv, b2, A, N);
        matmul128<<<mmb, 256, 0, stream>>>(A, W3, B, dinv, N, 128, 0);
        gcn_gather<<<ngb, 256, 0, stream>>>(B, csr_src, offs, counts, dinv, b3, A, N);
        matmul128<<<mmb, 256, 0, stream>>>(A, We, B, nullptr, N, 256, 0);
        matmul128<<<mmb, 256, 0, stream>>>(A, We + 128 * 128, B, nullptr, N, 256, 128);
        edge_mlp<<<emb, 256, 0, stream>>>(B, src, dst, ea + (size_t)t * E * 7,
                                          We + 256 * 128, be, Wg, acc + t, E);
    }
    write_out<<<1, 64, 0, stream>>>(acc, bg, (float*)d_out, 1.0f / (float)E, T);
}